// Round 1
// baseline (2254.386 us; speedup 1.0000x reference)
//
#include <hip/hip_runtime.h>

#define B_SZ 4
#define T_SZ 2048
#define D_SZ 1024
#define H_SZ 16
#define DK_SZ 64
#define M_SZ (B_SZ * T_SZ)  // 8192

// ---------------------------------------------------------------------------
// GEMM: C = A @ W^T + bias
//   A: [M, 1024] row-major; W: [1024, 1024] row-major (out, in)
//   headLayout=1 -> write C as [B, H, T, DK]; else [M, 1024]
// 64x64 tile, BK=16, 256 threads, 4x4 microtile per thread.
// LDS pad = 68 floats (272B = 17*16B) keeps ds_read_b128 16B-aligned.
// ---------------------------------------------------------------------------
__global__ __launch_bounds__(256)
void gemm_bias_kernel(const float* __restrict__ A, const float* __restrict__ W,
                      const float* __restrict__ bias, float* __restrict__ C,
                      int headLayout)
{
    __shared__ float As[16][68];
    __shared__ float Bs[16][68];
    const int K = D_SZ;
    const int m0 = blockIdx.x * 64;
    const int n0 = blockIdx.y * 64;
    const int tid = threadIdx.x;
    const int tx = tid & 15, ty = tid >> 4;
    const int lrow = tid >> 2;          // 0..63
    const int lq = (tid & 3) << 2;      // 0,4,8,12

    float acc[4][4] = {};

    const float* aptr = A + (size_t)(m0 + lrow) * K + lq;
    const float* wptr = W + (size_t)(n0 + lrow) * K + lq;

    for (int k0 = 0; k0 < K; k0 += 16) {
        float4 av = *(const float4*)(aptr + k0);
        float4 wv = *(const float4*)(wptr + k0);
        __syncthreads();
        As[lq + 0][lrow] = av.x; As[lq + 1][lrow] = av.y;
        As[lq + 2][lrow] = av.z; As[lq + 3][lrow] = av.w;
        Bs[lq + 0][lrow] = wv.x; Bs[lq + 1][lrow] = wv.y;
        Bs[lq + 2][lrow] = wv.z; Bs[lq + 3][lrow] = wv.w;
        __syncthreads();
#pragma unroll
        for (int kk = 0; kk < 16; ++kk) {
            float a[4], b[4];
#pragma unroll
            for (int i = 0; i < 4; ++i) a[i] = As[kk][ty * 4 + i];
#pragma unroll
            for (int j = 0; j < 4; ++j) b[j] = Bs[kk][tx * 4 + j];
#pragma unroll
            for (int i = 0; i < 4; ++i)
#pragma unroll
                for (int j = 0; j < 4; ++j)
                    acc[i][j] += a[i] * b[j];
        }
    }

#pragma unroll
    for (int i = 0; i < 4; ++i) {
        const int m = m0 + ty * 4 + i;
        const int nb = n0 + tx * 4;
        float4 o;
        o.x = acc[i][0] + bias[nb + 0];
        o.y = acc[i][1] + bias[nb + 1];
        o.z = acc[i][2] + bias[nb + 2];
        o.w = acc[i][3] + bias[nb + 3];
        if (headLayout) {
            const int b = m >> 11, t = m & (T_SZ - 1);
            const int h = nb >> 6, d = nb & 63;
            *(float4*)&C[(((size_t)(b * H_SZ + h)) * T_SZ + t) * DK_SZ + d] = o;
        } else {
            *(float4*)&C[(size_t)m * D_SZ + nb] = o;
        }
    }
}

// ---------------------------------------------------------------------------
// RoPE in-place on q/k in [B,H,T,DK] layout. One thread per (bh, t, j<32) pair.
// cos/sin: [T, 1, DK], broadcast over heads.
// ---------------------------------------------------------------------------
__global__ __launch_bounds__(256)
void rope_kernel(float* __restrict__ q, float* __restrict__ k,
                 const float* __restrict__ cosb, const float* __restrict__ sinb)
{
    const int idx = blockIdx.x * blockDim.x + threadIdx.x;
    const int j = idx & 31;
    const int t = (idx >> 5) & (T_SZ - 1);
    const int bh = idx >> 16;            // 32*2048 = 2^16 per (b,h)
    const float c1 = cosb[t * DK_SZ + j],      s1 = sinb[t * DK_SZ + j];
    const float c2 = cosb[t * DK_SZ + j + 32], s2 = sinb[t * DK_SZ + j + 32];
    const size_t base = ((size_t)bh * T_SZ + t) * DK_SZ + j;
    const float q1 = q[base], q2 = q[base + 32];
    q[base]      = q1 * c1 - q2 * s1;
    q[base + 32] = q2 * c2 + q1 * s2;
    const float k1 = k[base], k2 = k[base + 32];
    k[base]      = k1 * c1 - k2 * s1;
    k[base + 32] = k2 * c2 + k1 * s2;
}

// ---------------------------------------------------------------------------
// Flash-style attention. One block = (b,h) x 64 q-rows. 256 threads, 4x4
// microtiles. Online softmax; row stats reduced with __shfl_xor across the
// 16 tx lanes that share a row (same wave, same ty). Output -> [B,T,D].
// ---------------------------------------------------------------------------
__global__ __launch_bounds__(256)
void attn_kernel(const float* __restrict__ qb, const float* __restrict__ kb,
                 const float* __restrict__ vb, const unsigned char* __restrict__ mask,
                 float* __restrict__ ob)
{
    __shared__ float QsT[64][68];   // [d][q_row]
    __shared__ float KsT[64][68];   // [d][k_row]
    __shared__ float Vs[64][68];    // [k_row][d]
    __shared__ float SsT[64][68];   // [k_col][q_row]  (P transposed)

    const int bh = blockIdx.y;
    const int b = bh >> 4, h = bh & 15;
    const int q0 = blockIdx.x * 64;
    const int tid = threadIdx.x;
    const int tx = tid & 15, ty = tid >> 4;
    const int r0 = ty * 4, c0 = tx * 4;
    const int lrow = tid >> 2;          // 0..63
    const int lq = (tid & 3) << 4;      // 0,16,32,48

    const float* qsrc = qb + ((size_t)bh * T_SZ + q0) * DK_SZ;
#pragma unroll
    for (int w = 0; w < 4; ++w) {
        float4 v = *(const float4*)&qsrc[lrow * DK_SZ + lq + w * 4];
        QsT[lq + w * 4 + 0][lrow] = v.x;
        QsT[lq + w * 4 + 1][lrow] = v.y;
        QsT[lq + w * 4 + 2][lrow] = v.z;
        QsT[lq + w * 4 + 3][lrow] = v.w;
    }

    float accO[4][4] = {};
    float m_i[4], l_i[4];
#pragma unroll
    for (int i = 0; i < 4; ++i) { m_i[i] = -1e30f; l_i[i] = 0.f; }

    const float* ksrc = kb + (size_t)bh * T_SZ * DK_SZ;
    const float* vsrc = vb + (size_t)bh * T_SZ * DK_SZ;
    const unsigned char* mbase = mask + ((size_t)b * T_SZ + q0) * T_SZ;

    for (int kt = 0; kt < T_SZ; kt += 64) {
        __syncthreads();
#pragma unroll
        for (int w = 0; w < 4; ++w) {
            float4 kv = *(const float4*)&ksrc[(size_t)(kt + lrow) * DK_SZ + lq + w * 4];
            KsT[lq + w * 4 + 0][lrow] = kv.x;
            KsT[lq + w * 4 + 1][lrow] = kv.y;
            KsT[lq + w * 4 + 2][lrow] = kv.z;
            KsT[lq + w * 4 + 3][lrow] = kv.w;
            float4 vv = *(const float4*)&vsrc[(size_t)(kt + lrow) * DK_SZ + lq + w * 4];
            *(float4*)&Vs[lrow][lq + w * 4] = vv;
        }
        __syncthreads();

        // S = Q K^T for this tile
        float accS[4][4] = {};
        for (int d = 0; d < 64; ++d) {
            float a[4], bb[4];
#pragma unroll
            for (int i = 0; i < 4; ++i) a[i] = QsT[d][r0 + i];
#pragma unroll
            for (int j = 0; j < 4; ++j) bb[j] = KsT[d][c0 + j];
#pragma unroll
            for (int i = 0; i < 4; ++i)
#pragma unroll
                for (int j = 0; j < 4; ++j)
                    accS[i][j] += a[i] * bb[j];
        }

        // scale + mask
        float sv[4][4];
#pragma unroll
        for (int i = 0; i < 4; ++i) {
            uchar4 mv = *(const uchar4*)&mbase[(size_t)(r0 + i) * T_SZ + kt + c0];
            sv[i][0] = mv.x ? -1e30f : accS[i][0] * 0.125f;
            sv[i][1] = mv.y ? -1e30f : accS[i][1] * 0.125f;
            sv[i][2] = mv.z ? -1e30f : accS[i][2] * 0.125f;
            sv[i][3] = mv.w ? -1e30f : accS[i][3] * 0.125f;
        }

        // row max across the 16 tx lanes (same wave)
        float pmax[4];
#pragma unroll
        for (int i = 0; i < 4; ++i)
            pmax[i] = fmaxf(fmaxf(sv[i][0], sv[i][1]), fmaxf(sv[i][2], sv[i][3]));
        for (int off = 1; off < 16; off <<= 1) {
#pragma unroll
            for (int i = 0; i < 4; ++i)
                pmax[i] = fmaxf(pmax[i], __shfl_xor(pmax[i], off, 64));
        }

        float alpha[4], psum[4];
#pragma unroll
        for (int i = 0; i < 4; ++i) {
            const float mnew = fmaxf(m_i[i], pmax[i]);
            alpha[i] = __expf(m_i[i] - mnew);
            m_i[i] = mnew;
            psum[i] = 0.f;
#pragma unroll
            for (int j = 0; j < 4; ++j) {
                const float p = __expf(sv[i][j] - mnew);
                sv[i][j] = p;
                psum[i] += p;
            }
        }
        for (int off = 1; off < 16; off <<= 1) {
#pragma unroll
            for (int i = 0; i < 4; ++i)
                psum[i] += __shfl_xor(psum[i], off, 64);
        }
#pragma unroll
        for (int i = 0; i < 4; ++i)
            l_i[i] = l_i[i] * alpha[i] + psum[i];

        // store P transposed: SsT[c][r]
#pragma unroll
        for (int j = 0; j < 4; ++j) {
            float4 pv = make_float4(sv[0][j], sv[1][j], sv[2][j], sv[3][j]);
            *(float4*)&SsT[c0 + j][r0] = pv;
        }
        __syncthreads();

        // O = O*alpha + P @ V
#pragma unroll
        for (int i = 0; i < 4; ++i)
#pragma unroll
            for (int j = 0; j < 4; ++j)
                accO[i][j] *= alpha[i];
        for (int kk = 0; kk < 64; ++kk) {
            float p[4], vv[4];
#pragma unroll
            for (int i = 0; i < 4; ++i) p[i] = SsT[kk][r0 + i];
#pragma unroll
            for (int j = 0; j < 4; ++j) vv[j] = Vs[kk][c0 + j];
#pragma unroll
            for (int i = 0; i < 4; ++i)
#pragma unroll
                for (int j = 0; j < 4; ++j)
                    accO[i][j] += p[i] * vv[j];
        }
    }

#pragma unroll
    for (int i = 0; i < 4; ++i) {
        const float inv = 1.f / l_i[i];
        const int t = q0 + r0 + i;
        float4 o = make_float4(accO[i][0] * inv, accO[i][1] * inv,
                               accO[i][2] * inv, accO[i][3] * inv);
        *(float4*)&ob[((size_t)(b * T_SZ + t)) * D_SZ + h * DK_SZ + c0] = o;
    }
}

// ---------------------------------------------------------------------------
extern "C" void kernel_launch(void* const* d_in, const int* in_sizes, int n_in,
                              void* d_out, int out_size, void* d_ws, size_t ws_size,
                              hipStream_t stream)
{
    const float* query = (const float*)d_in[0];
    const float* key   = (const float*)d_in[1];
    const float* value = (const float*)d_in[2];
    const float* cosb  = (const float*)d_in[3];
    const float* sinb  = (const float*)d_in[4];
    const unsigned char* mask = (const unsigned char*)d_in[5];
    const float* Wq = (const float*)d_in[6];
    const float* bq = (const float*)d_in[7];
    const float* Wk = (const float*)d_in[8];
    const float* bk = (const float*)d_in[9];
    const float* Wv = (const float*)d_in[10];
    const float* bv = (const float*)d_in[11];
    const float* Wo = (const float*)d_in[12];
    const float* bo = (const float*)d_in[13];
    float* out = (float*)d_out;

    float* ws = (float*)d_ws;
    const size_t buf = (size_t)B_SZ * H_SZ * T_SZ * DK_SZ;  // 8388608 floats
    float* qbuf = ws;
    float* kbuf = ws + buf;
    float* vbuf = ws + 2 * buf;
    float* abuf = ws + 3 * buf;   // attention output in [B,T,D]

    dim3 gg(M_SZ / 64, D_SZ / 64);
    gemm_bias_kernel<<<gg, 256, 0, stream>>>(query, Wq, bq, qbuf, 1);
    gemm_bias_kernel<<<gg, 256, 0, stream>>>(key,   Wk, bk, kbuf, 1);
    gemm_bias_kernel<<<gg, 256, 0, stream>>>(value, Wv, bv, vbuf, 1);

    const int ropeN = B_SZ * H_SZ * T_SZ * 32;
    rope_kernel<<<ropeN / 256, 256, 0, stream>>>(qbuf, kbuf, cosb, sinb);

    attn_kernel<<<dim3(T_SZ / 64, B_SZ * H_SZ), 256, 0, stream>>>(
        qbuf, kbuf, vbuf, mask, abuf);

    gemm_bias_kernel<<<gg, 256, 0, stream>>>(abuf, Wo, bo, out, 0);
}

// Round 2
// 1615.047 us; speedup vs baseline: 1.3959x; 1.3959x over previous
//
#include <hip/hip_runtime.h>

#define B_SZ 4
#define T_SZ 2048
#define D_SZ 1024
#define H_SZ 16
#define DK_SZ 64
#define M_SZ (B_SZ * T_SZ)  // 8192

typedef __attribute__((ext_vector_type(8))) short bf16x8;
typedef __attribute__((ext_vector_type(4))) short bf16x4;
typedef __attribute__((ext_vector_type(4))) float f32x4;

static __device__ inline short f2bf(float x) {
    union { float f; unsigned u; } v; v.f = x;
    unsigned r = v.u + 0x7fff + ((v.u >> 16) & 1);
    return (short)(r >> 16);
}
static __device__ inline float bf2f(short h) {
    union { float f; unsigned u; } v;
    v.u = ((unsigned)(unsigned short)h) << 16;
    return v.f;
}

#define MFMA16(a, b, c) __builtin_amdgcn_mfma_f32_16x16x32_bf16((a), (b), (c), 0, 0, 0)

// ---------------------------------------------------------------------------
// GEMM: C = A @ W^T + bias  (unchanged fp32 baseline this round)
// ---------------------------------------------------------------------------
__global__ __launch_bounds__(256)
void gemm_bias_kernel(const float* __restrict__ A, const float* __restrict__ W,
                      const float* __restrict__ bias, float* __restrict__ C,
                      int headLayout)
{
    __shared__ float As[16][68];
    __shared__ float Bs[16][68];
    const int K = D_SZ;
    const int m0 = blockIdx.x * 64;
    const int n0 = blockIdx.y * 64;
    const int tid = threadIdx.x;
    const int tx = tid & 15, ty = tid >> 4;
    const int lrow = tid >> 2;
    const int lq = (tid & 3) << 2;

    float acc[4][4] = {};

    const float* aptr = A + (size_t)(m0 + lrow) * K + lq;
    const float* wptr = W + (size_t)(n0 + lrow) * K + lq;

    for (int k0 = 0; k0 < K; k0 += 16) {
        float4 av = *(const float4*)(aptr + k0);
        float4 wv = *(const float4*)(wptr + k0);
        __syncthreads();
        As[lq + 0][lrow] = av.x; As[lq + 1][lrow] = av.y;
        As[lq + 2][lrow] = av.z; As[lq + 3][lrow] = av.w;
        Bs[lq + 0][lrow] = wv.x; Bs[lq + 1][lrow] = wv.y;
        Bs[lq + 2][lrow] = wv.z; Bs[lq + 3][lrow] = wv.w;
        __syncthreads();
#pragma unroll
        for (int kk = 0; kk < 16; ++kk) {
            float a[4], b[4];
#pragma unroll
            for (int i = 0; i < 4; ++i) a[i] = As[kk][ty * 4 + i];
#pragma unroll
            for (int j = 0; j < 4; ++j) b[j] = Bs[kk][tx * 4 + j];
#pragma unroll
            for (int i = 0; i < 4; ++i)
#pragma unroll
                for (int j = 0; j < 4; ++j)
                    acc[i][j] += a[i] * b[j];
        }
    }

#pragma unroll
    for (int i = 0; i < 4; ++i) {
        const int m = m0 + ty * 4 + i;
        const int nb = n0 + tx * 4;
        float4 o;
        o.x = acc[i][0] + bias[nb + 0];
        o.y = acc[i][1] + bias[nb + 1];
        o.z = acc[i][2] + bias[nb + 2];
        o.w = acc[i][3] + bias[nb + 3];
        if (headLayout) {
            const int b = m >> 11, t = m & (T_SZ - 1);
            const int h = nb >> 6, d = nb & 63;
            *(float4*)&C[(((size_t)(b * H_SZ + h)) * T_SZ + t) * DK_SZ + d] = o;
        } else {
            *(float4*)&C[(size_t)m * D_SZ + nb] = o;
        }
    }
}

// ---------------------------------------------------------------------------
// RoPE in-place on q/k in [B,H,T,DK] layout (unchanged).
// ---------------------------------------------------------------------------
__global__ __launch_bounds__(256)
void rope_kernel(float* __restrict__ q, float* __restrict__ k,
                 const float* __restrict__ cosb, const float* __restrict__ sinb)
{
    const int idx = blockIdx.x * blockDim.x + threadIdx.x;
    const int j = idx & 31;
    const int t = (idx >> 5) & (T_SZ - 1);
    const int bh = idx >> 16;
    const float c1 = cosb[t * DK_SZ + j],      s1 = sinb[t * DK_SZ + j];
    const float c2 = cosb[t * DK_SZ + j + 32], s2 = sinb[t * DK_SZ + j + 32];
    const size_t base = ((size_t)bh * T_SZ + t) * DK_SZ + j;
    const float q1 = q[base], q2 = q[base + 32];
    q[base]      = q1 * c1 - q2 * s1;
    q[base + 32] = q2 * c2 + q1 * s2;
    const float k1 = k[base], k2 = k[base + 32];
    k[base]      = k1 * c1 - k2 * s1;
    k[base + 32] = k2 * c2 + k1 * s2;
}

// ---------------------------------------------------------------------------
// MFMA flash attention. Block = (b,h) x 64 q-rows, 4 waves x 16 q-rows each.
// QK^T in split-bf16 (3 MFMA products, ~2^-16 error); P,V plain bf16.
// LDS strides: 72 bf16 = 144 B (16B-aligned b128 reads, <=2-way conflicts).
// ---------------------------------------------------------------------------
__global__ __launch_bounds__(256)
void attn_mfma_kernel(const float* __restrict__ qb, const float* __restrict__ kb,
                      const float* __restrict__ vb,
                      const unsigned char* __restrict__ mask,
                      float* __restrict__ ob)
{
    __shared__ __align__(16) short Kh[64 * 72];
    __shared__ __align__(16) short Kl[64 * 72];
    __shared__ __align__(16) short Vt[64 * 72];   // V transposed: [d][k]
    __shared__ __align__(16) short Ps[4 * 16 * 72];  // per-wave P tiles

    const int bh = blockIdx.y;
    const int b = bh >> 4, h = bh & 15;
    const int q0 = blockIdx.x * 64;
    const int tid = threadIdx.x;
    const int wv = tid >> 6, lane = tid & 63;
    const int l15 = lane & 15, quad = lane >> 4;

    // ---- load this wave's Q fragments (A-layout: m=l15, k=quad*8+j), split hi/lo
    const int qrow = q0 + wv * 16 + l15;
    const float* qp = qb + ((size_t)bh * T_SZ + qrow) * DK_SZ;
    bf16x8 qh[2], ql[2];
#pragma unroll
    for (int s = 0; s < 2; ++s) {
        float f[8];
        *(float4*)&f[0] = *(const float4*)&qp[32 * s + quad * 8];
        *(float4*)&f[4] = *(const float4*)&qp[32 * s + quad * 8 + 4];
#pragma unroll
        for (int j = 0; j < 8; ++j) {
            short hi = f2bf(f[j]);
            qh[s][j] = hi;
            ql[s][j] = f2bf(f[j] - bf2f(hi));
        }
    }

    f32x4 accO[4];
#pragma unroll
    for (int nt = 0; nt < 4; ++nt) accO[nt] = (f32x4){0.f, 0.f, 0.f, 0.f};
    float m_i[4], l_i[4];
#pragma unroll
    for (int r = 0; r < 4; ++r) { m_i[r] = -1e30f; l_i[r] = 0.f; }

    const float* kbase = kb + (size_t)bh * T_SZ * DK_SZ;
    const float* vbase = vb + (size_t)bh * T_SZ * DK_SZ;
    const unsigned char* mrow = mask + ((size_t)b * T_SZ + q0) * T_SZ;

    const int srow = lane;       // staging: k-row handled by this lane
    const int sdb = wv * 16;     // staging: d-base handled by this wave
    short* pw = &Ps[wv * 16 * 72];

    for (int kt = 0; kt < T_SZ; kt += 64) {
        __syncthreads();
        // ---- stage K (hi/lo) and V^T into LDS
        const float* kr = kbase + (size_t)(kt + srow) * DK_SZ + sdb;
        const float* vr = vbase + (size_t)(kt + srow) * DK_SZ + sdb;
#pragma unroll
        for (int w4 = 0; w4 < 4; ++w4) {
            float4 kv = *(const float4*)(kr + 4 * w4);
            short h0 = f2bf(kv.x), h1 = f2bf(kv.y), h2 = f2bf(kv.z), h3 = f2bf(kv.w);
            bf16x4 hv = {h0, h1, h2, h3};
            bf16x4 lv = {f2bf(kv.x - bf2f(h0)), f2bf(kv.y - bf2f(h1)),
                         f2bf(kv.z - bf2f(h2)), f2bf(kv.w - bf2f(h3))};
            *(bf16x4*)&Kh[srow * 72 + sdb + 4 * w4] = hv;
            *(bf16x4*)&Kl[srow * 72 + sdb + 4 * w4] = lv;
            float4 vv = *(const float4*)(vr + 4 * w4);
            Vt[(sdb + 4 * w4 + 0) * 72 + srow] = f2bf(vv.x);
            Vt[(sdb + 4 * w4 + 1) * 72 + srow] = f2bf(vv.y);
            Vt[(sdb + 4 * w4 + 2) * 72 + srow] = f2bf(vv.z);
            Vt[(sdb + 4 * w4 + 3) * 72 + srow] = f2bf(vv.w);
        }
        __syncthreads();

        // ---- S = Q K^T (split bf16: qh*kh + ql*kh + qh*kl)
        f32x4 accS[4];
#pragma unroll
        for (int nt = 0; nt < 4; ++nt) {
            f32x4 acc = (f32x4){0.f, 0.f, 0.f, 0.f};
#pragma unroll
            for (int s = 0; s < 2; ++s) {
                const bf16x8 kh = *(const bf16x8*)&Kh[(nt * 16 + l15) * 72 + 32 * s + quad * 8];
                const bf16x8 kl = *(const bf16x8*)&Kl[(nt * 16 + l15) * 72 + 32 * s + quad * 8];
                acc = MFMA16(qh[s], kh, acc);
                acc = MFMA16(ql[s], kh, acc);
                acc = MFMA16(qh[s], kl, acc);
            }
            accS[nt] = acc;
        }

        // ---- scale + mask; C layout: row = quad*4+reg, col = nt*16+l15
        float sv[4][4];  // [nt][reg]
#pragma unroll
        for (int nt = 0; nt < 4; ++nt)
#pragma unroll
            for (int r = 0; r < 4; ++r) {
                const unsigned char mb =
                    mrow[(size_t)(quad * 4 + r) * T_SZ + kt + nt * 16 + l15];
                sv[nt][r] = mb ? -1e30f : accS[nt][r] * 0.125f;
            }

        // ---- online softmax (row stats across nt locally + 16 lanes of quad)
        float rmax[4];
#pragma unroll
        for (int r = 0; r < 4; ++r)
            rmax[r] = fmaxf(fmaxf(sv[0][r], sv[1][r]), fmaxf(sv[2][r], sv[3][r]));
#pragma unroll
        for (int off = 1; off < 16; off <<= 1)
#pragma unroll
            for (int r = 0; r < 4; ++r)
                rmax[r] = fmaxf(rmax[r], __shfl_xor(rmax[r], off, 64));

        float alpha[4];
#pragma unroll
        for (int r = 0; r < 4; ++r) {
            const float mnew = fmaxf(m_i[r], rmax[r]);
            alpha[r] = __expf(m_i[r] - mnew);
            m_i[r] = mnew;
        }
        float rsum[4] = {0.f, 0.f, 0.f, 0.f};
#pragma unroll
        for (int nt = 0; nt < 4; ++nt)
#pragma unroll
            for (int r = 0; r < 4; ++r) {
                const float p = __expf(sv[nt][r] - m_i[r]);
                sv[nt][r] = p;
                rsum[r] += p;
            }
#pragma unroll
        for (int off = 1; off < 16; off <<= 1)
#pragma unroll
            for (int r = 0; r < 4; ++r)
                rsum[r] += __shfl_xor(rsum[r], off, 64);
#pragma unroll
        for (int r = 0; r < 4; ++r)
            l_i[r] = l_i[r] * alpha[r] + rsum[r];

        // ---- P -> bf16 -> per-wave LDS tile (C layout write)
#pragma unroll
        for (int nt = 0; nt < 4; ++nt)
#pragma unroll
            for (int r = 0; r < 4; ++r)
                pw[(quad * 4 + r) * 72 + nt * 16 + l15] = f2bf(sv[nt][r]);

        // ---- rescale O, then O += P @ V
#pragma unroll
        for (int nt = 0; nt < 4; ++nt)
#pragma unroll
            for (int r = 0; r < 4; ++r)
                accO[nt][r] *= alpha[r];

        bf16x8 pa[2];
#pragma unroll
        for (int s = 0; s < 2; ++s)
            pa[s] = *(const bf16x8*)&pw[l15 * 72 + 32 * s + quad * 8];
#pragma unroll
        for (int nt = 0; nt < 4; ++nt)
#pragma unroll
            for (int s = 0; s < 2; ++s) {
                const bf16x8 vf = *(const bf16x8*)&Vt[(nt * 16 + l15) * 72 + 32 * s + quad * 8];
                accO[nt] = MFMA16(pa[s], vf, accO[nt]);
            }
    }

    // ---- epilogue: O / l -> [B,T,D]
#pragma unroll
    for (int r = 0; r < 4; ++r) {
        const float inv = 1.f / l_i[r];
        const int t = q0 + wv * 16 + quad * 4 + r;
        float* orow = ob + ((size_t)(b * T_SZ + t)) * D_SZ + h * DK_SZ;
#pragma unroll
        for (int nt = 0; nt < 4; ++nt)
            orow[nt * 16 + l15] = accO[nt][r] * inv;
    }
}

// ---------------------------------------------------------------------------
extern "C" void kernel_launch(void* const* d_in, const int* in_sizes, int n_in,
                              void* d_out, int out_size, void* d_ws, size_t ws_size,
                              hipStream_t stream)
{
    const float* query = (const float*)d_in[0];
    const float* key   = (const float*)d_in[1];
    const float* value = (const float*)d_in[2];
    const float* cosb  = (const float*)d_in[3];
    const float* sinb  = (const float*)d_in[4];
    const unsigned char* mask = (const unsigned char*)d_in[5];
    const float* Wq = (const float*)d_in[6];
    const float* bq = (const float*)d_in[7];
    const float* Wk = (const float*)d_in[8];
    const float* bk = (const float*)d_in[9];
    const float* Wv = (const float*)d_in[10];
    const float* bv = (const float*)d_in[11];
    const float* Wo = (const float*)d_in[12];
    const float* bo = (const float*)d_in[13];
    float* out = (float*)d_out;

    float* ws = (float*)d_ws;
    const size_t buf = (size_t)B_SZ * H_SZ * T_SZ * DK_SZ;
    float* qbuf = ws;
    float* kbuf = ws + buf;
    float* vbuf = ws + 2 * buf;
    float* abuf = ws + 3 * buf;

    dim3 gg(M_SZ / 64, D_SZ / 64);
    gemm_bias_kernel<<<gg, 256, 0, stream>>>(query, Wq, bq, qbuf, 1);
    gemm_bias_kernel<<<gg, 256, 0, stream>>>(key,   Wk, bk, kbuf, 1);
    gemm_bias_kernel<<<gg, 256, 0, stream>>>(value, Wv, bv, vbuf, 1);

    const int ropeN = B_SZ * H_SZ * T_SZ * 32;
    rope_kernel<<<ropeN / 256, 256, 0, stream>>>(qbuf, kbuf, cosb, sinb);

    attn_mfma_kernel<<<dim3(T_SZ / 64, B_SZ * H_SZ), 256, 0, stream>>>(
        qbuf, kbuf, vbuf, mask, abuf);

    gemm_bias_kernel<<<gg, 256, 0, stream>>>(abuf, Wo, bo, out, 0);
}

// Round 3
// 950.147 us; speedup vs baseline: 2.3727x; 1.6998x over previous
//
#include <hip/hip_runtime.h>

#define B_SZ 4
#define T_SZ 2048
#define D_SZ 1024
#define H_SZ 16
#define DK_SZ 64
#define M_SZ (B_SZ * T_SZ)  // 8192

typedef __attribute__((ext_vector_type(8))) short bf16x8;
typedef __attribute__((ext_vector_type(4))) short bf16x4;
typedef __attribute__((ext_vector_type(4))) float f32x4;

union fui { float f; unsigned u; };

static __device__ inline short f2bf(float x) {
    union { float f; unsigned u; } v; v.f = x;
    unsigned r = v.u + 0x7fff + ((v.u >> 16) & 1);
    return (short)(r >> 16);
}
static __device__ inline float bf2f(short h) {
    union { float f; unsigned u; } v;
    v.u = ((unsigned)(unsigned short)h) << 16;
    return v.f;
}

#define MFMA16(a, b, c) __builtin_amdgcn_mfma_f32_16x16x32_bf16((a), (b), (c), 0, 0, 0)

#define GLDS16(g, l) __builtin_amdgcn_global_load_lds(                        \
    (const __attribute__((address_space(1))) unsigned int*)(g),               \
    (__attribute__((address_space(3))) unsigned int*)(l), 16, 0, 0)

// Truncation-split of 8 fp32 into hi/lo bf16 fragments; v_perm packs pairs.
// hi = trunc16(f); lo = trunc16(f - hi). Dropped lo*lo term ~2^-16 relative.
static __device__ inline void split8(float4 f0, float4 f1, bf16x8* hi, bf16x8* lo)
{
    fui a[8];
    a[0].f = f0.x; a[1].f = f0.y; a[2].f = f0.z; a[3].f = f0.w;
    a[4].f = f1.x; a[5].f = f1.y; a[6].f = f1.z; a[7].f = f1.w;
    union { unsigned w[4]; bf16x8 v; } H, L;
#pragma unroll
    for (int p = 0; p < 4; ++p)
        H.w[p] = __builtin_amdgcn_perm(a[2 * p + 1].u, a[2 * p].u, 0x07060302);
#pragma unroll
    for (int j = 0; j < 8; ++j) {
        fui t; t.u = a[j].u & 0xffff0000u;
        fui r; r.f = a[j].f - t.f;
        a[j].u = r.u;
    }
#pragma unroll
    for (int p = 0; p < 4; ++p)
        L.w[p] = __builtin_amdgcn_perm(a[2 * p + 1].u, a[2 * p].u, 0x07060302);
    *hi = H.v; *lo = L.v;
}

// ---------------------------------------------------------------------------
// Pre-split a weight matrix (1024x1024 fp32) into hi/lo bf16 (truncation).
// One thread per 4 elements.
// ---------------------------------------------------------------------------
__global__ __launch_bounds__(256)
void wsplit_kernel(const float* __restrict__ W, short* __restrict__ Wh,
                   short* __restrict__ Wl)
{
    const int i = blockIdx.x * 256 + threadIdx.x;   // float4 index
    float4 f = ((const float4*)W)[i];
    fui a[4]; a[0].f = f.x; a[1].f = f.y; a[2].f = f.z; a[3].f = f.w;
    short h[4], l[4];
#pragma unroll
    for (int j = 0; j < 4; ++j) {
        h[j] = (short)(a[j].u >> 16);
        fui t; t.u = a[j].u & 0xffff0000u;
        fui r; r.f = a[j].f - t.f;
        l[j] = (short)(r.u >> 16);
    }
    union { short s[4]; short4 v; } H, L;
#pragma unroll
    for (int j = 0; j < 4; ++j) { H.s[j] = h[j]; L.s[j] = l[j]; }
    ((short4*)Wh)[i] = H.v;
    ((short4*)Wl)[i] = L.v;
}

// ---------------------------------------------------------------------------
// Split-bf16 MFMA GEMM: C = A @ W^T + bias, A fp32 [M,1024], W pre-split
// hi/lo bf16 [1024,1024] row-major. 128x128 tile, BK=32, 256 thr (4 waves,
// 64x64 quadrant each, 4x4 of 16x16x32 MFMA tiles, 3 products per tile).
// W staged via global_load_lds(16B); A loaded global->VGPR, split in-reg.
// headLayout=1 -> C as [B,H,T,DK]; else [M,1024].
// ---------------------------------------------------------------------------
__global__ __launch_bounds__(256)
void gemm_mfma_kernel(const float* __restrict__ A, const short* __restrict__ Wh,
                      const short* __restrict__ Wl, const float* __restrict__ bias,
                      float* __restrict__ C, int headLayout)
{
    __shared__ __align__(16) short Whs[128 * 32];
    __shared__ __align__(16) short Wls[128 * 32];

    const int m0 = blockIdx.x * 128, n0 = blockIdx.y * 128;
    const int tid = threadIdx.x;
    const int wv = tid >> 6, lane = tid & 63;
    const int wm = wv >> 1, wn = wv & 1;
    const int l15 = lane & 15, quad = lane >> 4;

    f32x4 acc[4][4];
#pragma unroll
    for (int mt = 0; mt < 4; ++mt)
#pragma unroll
        for (int nt = 0; nt < 4; ++nt)
            acc[mt][nt] = (f32x4){0.f, 0.f, 0.f, 0.f};

    // W staging: wave wv owns rows [wv*32, wv*32+32) of the 128-row tile,
    // as two 16-row chunks (each = 64 lanes x 16B, contiguous in LDS).
    const short* whg = Wh + (size_t)(n0 + wv * 32 + (lane >> 2)) * D_SZ + (lane & 3) * 8;
    const short* wlg = Wl + (size_t)(n0 + wv * 32 + (lane >> 2)) * D_SZ + (lane & 3) * 8;
    short* whl0 = &Whs[wv * 1024];
    short* wll0 = &Wls[wv * 1024];

    // A fragment row bases (fp32, direct global)
    const float* aB[4];
#pragma unroll
    for (int mt = 0; mt < 4; ++mt)
        aB[mt] = A + (size_t)(m0 + wm * 64 + mt * 16 + l15) * D_SZ + quad * 8;

    for (int k0 = 0; k0 < D_SZ; k0 += 32) {
        // A loads first (VGPR), then LDS-DMA issues; conversion overlaps DMA.
        float4 af0[4], af1[4];
#pragma unroll
        for (int mt = 0; mt < 4; ++mt) {
            af0[mt] = *(const float4*)(aB[mt] + k0);
            af1[mt] = *(const float4*)(aB[mt] + k0 + 4);
        }
        __syncthreads();   // prev iteration's b-frag reads done
        GLDS16(whg + k0,              whl0);
        GLDS16(whg + 16 * D_SZ + k0,  whl0 + 512);
        GLDS16(wlg + k0,              wll0);
        GLDS16(wlg + 16 * D_SZ + k0,  wll0 + 512);

        bf16x8 ah[4], al[4];
#pragma unroll
        for (int mt = 0; mt < 4; ++mt)
            split8(af0[mt], af1[mt], &ah[mt], &al[mt]);

        __syncthreads();   // W tile staged (vmcnt drained)

#pragma unroll
        for (int nt = 0; nt < 4; ++nt) {
            const int brow = (wn * 64 + nt * 16 + l15) * 32 + quad * 8;
            const bf16x8 bh = *(const bf16x8*)&Whs[brow];
            const bf16x8 bl = *(const bf16x8*)&Wls[brow];
#pragma unroll
            for (int mt = 0; mt < 4; ++mt) {
                acc[mt][nt] = MFMA16(ah[mt], bh, acc[mt][nt]);
                acc[mt][nt] = MFMA16(al[mt], bh, acc[mt][nt]);
                acc[mt][nt] = MFMA16(ah[mt], bl, acc[mt][nt]);
            }
        }
    }

    // epilogue: bias + store. C layout: row = quad*4+r, col = l15 per tile.
#pragma unroll
    for (int nt = 0; nt < 4; ++nt) {
        const int col = n0 + wn * 64 + nt * 16 + l15;
        const float bv = bias[col];
        if (headLayout) {
            const int h = col >> 6, d = col & 63;
#pragma unroll
            for (int mt = 0; mt < 4; ++mt)
#pragma unroll
                for (int r = 0; r < 4; ++r) {
                    const int m = m0 + wm * 64 + mt * 16 + quad * 4 + r;
                    const int b = m >> 11, t = m & (T_SZ - 1);
                    C[(((size_t)(b * H_SZ + h)) * T_SZ + t) * DK_SZ + d] =
                        acc[mt][nt][r] + bv;
                }
        } else {
#pragma unroll
            for (int mt = 0; mt < 4; ++mt)
#pragma unroll
                for (int r = 0; r < 4; ++r) {
                    const int m = m0 + wm * 64 + mt * 16 + quad * 4 + r;
                    C[(size_t)m * D_SZ + col] = acc[mt][nt][r] + bv;
                }
        }
    }
}

// ---------------------------------------------------------------------------
// RoPE in-place on q/k in [B,H,T,DK] layout (unchanged).
// ---------------------------------------------------------------------------
__global__ __launch_bounds__(256)
void rope_kernel(float* __restrict__ q, float* __restrict__ k,
                 const float* __restrict__ cosb, const float* __restrict__ sinb)
{
    const int idx = blockIdx.x * blockDim.x + threadIdx.x;
    const int j = idx & 31;
    const int t = (idx >> 5) & (T_SZ - 1);
    const int bh = idx >> 16;
    const float c1 = cosb[t * DK_SZ + j],      s1 = sinb[t * DK_SZ + j];
    const float c2 = cosb[t * DK_SZ + j + 32], s2 = sinb[t * DK_SZ + j + 32];
    const size_t base = ((size_t)bh * T_SZ + t) * DK_SZ + j;
    const float q1 = q[base], q2 = q[base + 32];
    q[base]      = q1 * c1 - q2 * s1;
    q[base + 32] = q2 * c2 + q1 * s2;
    const float k1 = k[base], k2 = k[base + 32];
    k[base]      = k1 * c1 - k2 * s1;
    k[base + 32] = k2 * c2 + k1 * s2;
}

// ---------------------------------------------------------------------------
// MFMA flash attention (unchanged from round 1).
// ---------------------------------------------------------------------------
__global__ __launch_bounds__(256)
void attn_mfma_kernel(const float* __restrict__ qb, const float* __restrict__ kb,
                      const float* __restrict__ vb,
                      const unsigned char* __restrict__ mask,
                      float* __restrict__ ob)
{
    __shared__ __align__(16) short Kh[64 * 72];
    __shared__ __align__(16) short Kl[64 * 72];
    __shared__ __align__(16) short Vt[64 * 72];   // V transposed: [d][k]
    __shared__ __align__(16) short Ps[4 * 16 * 72];  // per-wave P tiles

    const int bh = blockIdx.y;
    const int b = bh >> 4, h = bh & 15;
    const int q0 = blockIdx.x * 64;
    const int tid = threadIdx.x;
    const int wv = tid >> 6, lane = tid & 63;
    const int l15 = lane & 15, quad = lane >> 4;

    const int qrow = q0 + wv * 16 + l15;
    const float* qp = qb + ((size_t)bh * T_SZ + qrow) * DK_SZ;
    bf16x8 qh[2], ql[2];
#pragma unroll
    for (int s = 0; s < 2; ++s) {
        float f[8];
        *(float4*)&f[0] = *(const float4*)&qp[32 * s + quad * 8];
        *(float4*)&f[4] = *(const float4*)&qp[32 * s + quad * 8 + 4];
#pragma unroll
        for (int j = 0; j < 8; ++j) {
            short hi = f2bf(f[j]);
            qh[s][j] = hi;
            ql[s][j] = f2bf(f[j] - bf2f(hi));
        }
    }

    f32x4 accO[4];
#pragma unroll
    for (int nt = 0; nt < 4; ++nt) accO[nt] = (f32x4){0.f, 0.f, 0.f, 0.f};
    float m_i[4], l_i[4];
#pragma unroll
    for (int r = 0; r < 4; ++r) { m_i[r] = -1e30f; l_i[r] = 0.f; }

    const float* kbase = kb + (size_t)bh * T_SZ * DK_SZ;
    const float* vbase = vb + (size_t)bh * T_SZ * DK_SZ;
    const unsigned char* mrow = mask + ((size_t)b * T_SZ + q0) * T_SZ;

    const int srow = lane;
    const int sdb = wv * 16;
    short* pw = &Ps[wv * 16 * 72];

    for (int kt = 0; kt < T_SZ; kt += 64) {
        __syncthreads();
        const float* kr = kbase + (size_t)(kt + srow) * DK_SZ + sdb;
        const float* vr = vbase + (size_t)(kt + srow) * DK_SZ + sdb;
#pragma unroll
        for (int w4 = 0; w4 < 4; ++w4) {
            float4 kv = *(const float4*)(kr + 4 * w4);
            short h0 = f2bf(kv.x), h1 = f2bf(kv.y), h2 = f2bf(kv.z), h3 = f2bf(kv.w);
            bf16x4 hv = {h0, h1, h2, h3};
            bf16x4 lv = {f2bf(kv.x - bf2f(h0)), f2bf(kv.y - bf2f(h1)),
                         f2bf(kv.z - bf2f(h2)), f2bf(kv.w - bf2f(h3))};
            *(bf16x4*)&Kh[srow * 72 + sdb + 4 * w4] = hv;
            *(bf16x4*)&Kl[srow * 72 + sdb + 4 * w4] = lv;
            float4 vv = *(const float4*)(vr + 4 * w4);
            Vt[(sdb + 4 * w4 + 0) * 72 + srow] = f2bf(vv.x);
            Vt[(sdb + 4 * w4 + 1) * 72 + srow] = f2bf(vv.y);
            Vt[(sdb + 4 * w4 + 2) * 72 + srow] = f2bf(vv.z);
            Vt[(sdb + 4 * w4 + 3) * 72 + srow] = f2bf(vv.w);
        }
        __syncthreads();

        f32x4 accS[4];
#pragma unroll
        for (int nt = 0; nt < 4; ++nt) {
            f32x4 acc = (f32x4){0.f, 0.f, 0.f, 0.f};
#pragma unroll
            for (int s = 0; s < 2; ++s) {
                const bf16x8 kh = *(const bf16x8*)&Kh[(nt * 16 + l15) * 72 + 32 * s + quad * 8];
                const bf16x8 kl = *(const bf16x8*)&Kl[(nt * 16 + l15) * 72 + 32 * s + quad * 8];
                acc = MFMA16(qh[s], kh, acc);
                acc = MFMA16(ql[s], kh, acc);
                acc = MFMA16(qh[s], kl, acc);
            }
            accS[nt] = acc;
        }

        float sv[4][4];
#pragma unroll
        for (int nt = 0; nt < 4; ++nt)
#pragma unroll
            for (int r = 0; r < 4; ++r) {
                const unsigned char mb =
                    mrow[(size_t)(quad * 4 + r) * T_SZ + kt + nt * 16 + l15];
                sv[nt][r] = mb ? -1e30f : accS[nt][r] * 0.125f;
            }

        float rmax[4];
#pragma unroll
        for (int r = 0; r < 4; ++r)
            rmax[r] = fmaxf(fmaxf(sv[0][r], sv[1][r]), fmaxf(sv[2][r], sv[3][r]));
#pragma unroll
        for (int off = 1; off < 16; off <<= 1)
#pragma unroll
            for (int r = 0; r < 4; ++r)
                rmax[r] = fmaxf(rmax[r], __shfl_xor(rmax[r], off, 64));

        float alpha[4];
#pragma unroll
        for (int r = 0; r < 4; ++r) {
            const float mnew = fmaxf(m_i[r], rmax[r]);
            alpha[r] = __expf(m_i[r] - mnew);
            m_i[r] = mnew;
        }
        float rsum[4] = {0.f, 0.f, 0.f, 0.f};
#pragma unroll
        for (int nt = 0; nt < 4; ++nt)
#pragma unroll
            for (int r = 0; r < 4; ++r) {
                const float p = __expf(sv[nt][r] - m_i[r]);
                sv[nt][r] = p;
                rsum[r] += p;
            }
#pragma unroll
        for (int off = 1; off < 16; off <<= 1)
#pragma unroll
            for (int r = 0; r < 4; ++r)
                rsum[r] += __shfl_xor(rsum[r], off, 64);
#pragma unroll
        for (int r = 0; r < 4; ++r)
            l_i[r] = l_i[r] * alpha[r] + rsum[r];

#pragma unroll
        for (int nt = 0; nt < 4; ++nt)
#pragma unroll
            for (int r = 0; r < 4; ++r)
                pw[(quad * 4 + r) * 72 + nt * 16 + l15] = f2bf(sv[nt][r]);

#pragma unroll
        for (int nt = 0; nt < 4; ++nt)
#pragma unroll
            for (int r = 0; r < 4; ++r)
                accO[nt][r] *= alpha[r];

        bf16x8 pa[2];
#pragma unroll
        for (int s = 0; s < 2; ++s)
            pa[s] = *(const bf16x8*)&pw[l15 * 72 + 32 * s + quad * 8];
#pragma unroll
        for (int nt = 0; nt < 4; ++nt)
#pragma unroll
            for (int s = 0; s < 2; ++s) {
                const bf16x8 vf = *(const bf16x8*)&Vt[(nt * 16 + l15) * 72 + 32 * s + quad * 8];
                accO[nt] = MFMA16(pa[s], vf, accO[nt]);
            }
    }

#pragma unroll
    for (int r = 0; r < 4; ++r) {
        const float inv = 1.f / l_i[r];
        const int t = q0 + wv * 16 + quad * 4 + r;
        float* orow = ob + ((size_t)(b * T_SZ + t)) * D_SZ + h * DK_SZ;
#pragma unroll
        for (int nt = 0; nt < 4; ++nt)
            orow[nt * 16 + l15] = accO[nt][r] * inv;
    }
}

// ---------------------------------------------------------------------------
extern "C" void kernel_launch(void* const* d_in, const int* in_sizes, int n_in,
                              void* d_out, int out_size, void* d_ws, size_t ws_size,
                              hipStream_t stream)
{
    const float* query = (const float*)d_in[0];
    const float* key   = (const float*)d_in[1];
    const float* value = (const float*)d_in[2];
    const float* cosb  = (const float*)d_in[3];
    const float* sinb  = (const float*)d_in[4];
    const unsigned char* mask = (const unsigned char*)d_in[5];
    const float* Wq = (const float*)d_in[6];
    const float* bq = (const float*)d_in[7];
    const float* Wk = (const float*)d_in[8];
    const float* bk = (const float*)d_in[9];
    const float* Wv = (const float*)d_in[10];
    const float* bv = (const float*)d_in[11];
    const float* Wo = (const float*)d_in[12];
    const float* bo = (const float*)d_in[13];
    float* out = (float*)d_out;

    float* ws = (float*)d_ws;
    const size_t buf = (size_t)B_SZ * H_SZ * T_SZ * DK_SZ;   // 8M floats
    float* qbuf = ws;
    float* kbuf = ws + buf;
    float* vbuf = ws + 2 * buf;
    float* abuf = ws + 3 * buf;
    short* wsp = (short*)(ws + 4 * buf);
    const size_t wlen = (size_t)D_SZ * D_SZ;                 // 1M shorts
    short* wqh = wsp;            short* wql = wsp + wlen;
    short* wkh = wsp + 2 * wlen; short* wkl = wsp + 3 * wlen;
    short* wvh = wsp + 4 * wlen; short* wvl = wsp + 5 * wlen;
    short* woh = wsp + 6 * wlen; short* wol = wsp + 7 * wlen;

    const int wsBlocks = (int)(wlen / 4 / 256);   // 1024
    wsplit_kernel<<<wsBlocks, 256, 0, stream>>>(Wq, wqh, wql);
    wsplit_kernel<<<wsBlocks, 256, 0, stream>>>(Wk, wkh, wkl);
    wsplit_kernel<<<wsBlocks, 256, 0, stream>>>(Wv, wvh, wvl);
    wsplit_kernel<<<wsBlocks, 256, 0, stream>>>(Wo, woh, wol);

    dim3 gg(M_SZ / 128, D_SZ / 128);
    gemm_mfma_kernel<<<gg, 256, 0, stream>>>(query, wqh, wql, bq, qbuf, 1);
    gemm_mfma_kernel<<<gg, 256, 0, stream>>>(key,   wkh, wkl, bk, kbuf, 1);
    gemm_mfma_kernel<<<gg, 256, 0, stream>>>(value, wvh, wvl, bv, vbuf, 1);

    const int ropeN = B_SZ * H_SZ * T_SZ * 32;
    rope_kernel<<<ropeN / 256, 256, 0, stream>>>(qbuf, kbuf, cosb, sinb);

    attn_mfma_kernel<<<dim3(T_SZ / 64, B_SZ * H_SZ), 256, 0, stream>>>(
        qbuf, kbuf, vbuf, mask, abuf);

    gemm_mfma_kernel<<<gg, 256, 0, stream>>>(abuf, woh, wol, bo, out, 0);
}

// Round 4
// 782.458 us; speedup vs baseline: 2.8812x; 1.2143x over previous
//
#include <hip/hip_runtime.h>

#define B_SZ 4
#define T_SZ 2048
#define D_SZ 1024
#define H_SZ 16
#define DK_SZ 64
#define M_SZ (B_SZ * T_SZ)  // 8192

typedef __attribute__((ext_vector_type(8))) short bf16x8;
typedef __attribute__((ext_vector_type(4))) short bf16x4;
typedef __attribute__((ext_vector_type(4))) float f32x4;

union fui { float f; unsigned u; };

static __device__ inline short f2bf(float x) {            // RNE-ish rounding
    union { float f; unsigned u; } v; v.f = x;
    unsigned r = v.u + 0x7fff + ((v.u >> 16) & 1);
    return (short)(r >> 16);
}
// truncation split: hi = trunc16(f), lo = trunc16(f - hi); |err| ~ 2^-17 rel
static __device__ inline void split1(float f, short* h, short* l) {
    fui a; a.f = f;
    *h = (short)(a.u >> 16);
    fui t; t.u = a.u & 0xffff0000u;
    fui r; r.f = f - t.f;
    *l = (short)(r.u >> 16);
}

#define MFMA16(a, b, c) __builtin_amdgcn_mfma_f32_16x16x32_bf16((a), (b), (c), 0, 0, 0)

#define GLDS16(g, l) __builtin_amdgcn_global_load_lds(                        \
    (const __attribute__((address_space(1))) unsigned int*)(g),               \
    (__attribute__((address_space(3))) unsigned int*)(l), 16, 0, 0)

// Split 8 fp32 -> hi/lo bf16x8 (truncation), v_perm pair packing.
static __device__ inline void split8(float4 f0, float4 f1, bf16x8* hi, bf16x8* lo)
{
    fui a[8];
    a[0].f = f0.x; a[1].f = f0.y; a[2].f = f0.z; a[3].f = f0.w;
    a[4].f = f1.x; a[5].f = f1.y; a[6].f = f1.z; a[7].f = f1.w;
    union { unsigned w[4]; bf16x8 v; } H, L;
#pragma unroll
    for (int p = 0; p < 4; ++p)
        H.w[p] = __builtin_amdgcn_perm(a[2 * p + 1].u, a[2 * p].u, 0x07060302);
#pragma unroll
    for (int j = 0; j < 8; ++j) {
        fui t; t.u = a[j].u & 0xffff0000u;
        fui r; r.f = a[j].f - t.f;
        a[j].u = r.u;
    }
#pragma unroll
    for (int p = 0; p < 4; ++p)
        L.w[p] = __builtin_amdgcn_perm(a[2 * p + 1].u, a[2 * p].u, 0x07060302);
    *hi = H.v; *lo = L.v;
}

// ---------------------------------------------------------------------------
// Pre-split weight matrix into hi/lo bf16.
// ---------------------------------------------------------------------------
__global__ __launch_bounds__(256)
void wsplit_kernel(const float* __restrict__ W, short* __restrict__ Wh,
                   short* __restrict__ Wl)
{
    const int i = blockIdx.x * 256 + threadIdx.x;
    float4 f = ((const float4*)W)[i];
    fui a[4]; a[0].f = f.x; a[1].f = f.y; a[2].f = f.z; a[3].f = f.w;
    union { short s[4]; short4 v; } H, L;
#pragma unroll
    for (int j = 0; j < 4; ++j) {
        H.s[j] = (short)(a[j].u >> 16);
        fui t; t.u = a[j].u & 0xffff0000u;
        fui r; r.f = a[j].f - t.f;
        L.s[j] = (short)(r.u >> 16);
    }
    ((short4*)Wh)[i] = H.v;
    ((short4*)Wl)[i] = L.v;
}

// ---------------------------------------------------------------------------
// Mask summary: flags[b][qt][kt] = any(mask) over each 64x64 tile.
// One wave per flag; 1024 blocks x 256 thr.
// ---------------------------------------------------------------------------
__global__ __launch_bounds__(256)
void mask_flags_kernel(const unsigned char* __restrict__ mask, int* __restrict__ flags)
{
    const int f = blockIdx.x * 4 + (threadIdx.x >> 6);
    const int lane = threadIdx.x & 63;
    const int b = f >> 10, qt = (f >> 5) & 31, kt = f & 31;
    const unsigned char* base = mask + ((size_t)b * T_SZ + qt * 64) * T_SZ + kt * 64;
    bool nz = false;
#pragma unroll
    for (int i = 0; i < 4; ++i) {
        const int c = lane + 64 * i;
        const int row = c >> 2, off = (c & 3) * 16;
        uint4 v = *(const uint4*)(base + (size_t)row * T_SZ + off);
        nz |= ((v.x | v.y | v.z | v.w) != 0);
    }
    unsigned long long bal = __ballot(nz);
    if (lane == 0) flags[f] = (bal != 0) ? 1 : 0;
}

// ---------------------------------------------------------------------------
// Fused QKV projection. grid (64, 24): by>>3 selects q/k/v, by&7 the n-block.
// 128x128 tile, BK=32, 4 waves, split-bf16 (3 MFMA products).
// Epilogue: q/k -> RoPE in-register (pairs nt,nt+2 are d,d+32 of one head),
// q pre-scaled by 1/8, written as hi/lo bf16 [b,h][t][d]. v -> bf16.
// ---------------------------------------------------------------------------
__global__ __launch_bounds__(256)
void qkv_mfma_kernel(const float* __restrict__ Aq, const float* __restrict__ Ak,
                     const float* __restrict__ Av,
                     const short* __restrict__ Wqh, const short* __restrict__ Wql,
                     const short* __restrict__ Wkh, const short* __restrict__ Wkl,
                     const short* __restrict__ Wvh, const short* __restrict__ Wvl,
                     const float* __restrict__ bq, const float* __restrict__ bk,
                     const float* __restrict__ bv,
                     const float* __restrict__ cosb, const float* __restrict__ sinb,
                     short* __restrict__ Qh, short* __restrict__ Ql,
                     short* __restrict__ Kh, short* __restrict__ Kl,
                     short* __restrict__ Vb)
{
    __shared__ __align__(16) short Whs[128 * 32];
    __shared__ __align__(16) short Wls[128 * 32];

    const int which = blockIdx.y >> 3;
    const int m0 = blockIdx.x * 128, n0 = (blockIdx.y & 7) * 128;
    const float* A  = (which == 0) ? Aq  : (which == 1) ? Ak  : Av;
    const short* Wh = (which == 0) ? Wqh : (which == 1) ? Wkh : Wvh;
    const short* Wl = (which == 0) ? Wql : (which == 1) ? Wkl : Wvl;
    const float* bias = (which == 0) ? bq : (which == 1) ? bk : bv;

    const int tid = threadIdx.x;
    const int wv = tid >> 6, lane = tid & 63;
    const int wm = wv >> 1, wn = wv & 1;
    const int l15 = lane & 15, quad = lane >> 4;

    f32x4 acc[4][4];
#pragma unroll
    for (int mt = 0; mt < 4; ++mt)
#pragma unroll
        for (int nt = 0; nt < 4; ++nt)
            acc[mt][nt] = (f32x4){0.f, 0.f, 0.f, 0.f};

    const short* whg = Wh + (size_t)(n0 + wv * 32 + (lane >> 2)) * D_SZ + (lane & 3) * 8;
    const short* wlg = Wl + (size_t)(n0 + wv * 32 + (lane >> 2)) * D_SZ + (lane & 3) * 8;
    short* whl0 = &Whs[wv * 1024];
    short* wll0 = &Wls[wv * 1024];

    const float* aB[4];
#pragma unroll
    for (int mt = 0; mt < 4; ++mt)
        aB[mt] = A + (size_t)(m0 + wm * 64 + mt * 16 + l15) * D_SZ + quad * 8;

    for (int k0 = 0; k0 < D_SZ; k0 += 32) {
        float4 af0[4], af1[4];
#pragma unroll
        for (int mt = 0; mt < 4; ++mt) {
            af0[mt] = *(const float4*)(aB[mt] + k0);
            af1[mt] = *(const float4*)(aB[mt] + k0 + 4);
        }
        __syncthreads();
        GLDS16(whg + k0,             whl0);
        GLDS16(whg + 16 * D_SZ + k0, whl0 + 512);
        GLDS16(wlg + k0,             wll0);
        GLDS16(wlg + 16 * D_SZ + k0, wll0 + 512);

        bf16x8 ah[4], al[4];
#pragma unroll
        for (int mt = 0; mt < 4; ++mt)
            split8(af0[mt], af1[mt], &ah[mt], &al[mt]);

        __syncthreads();

#pragma unroll
        for (int nt = 0; nt < 4; ++nt) {
            const int brow = (wn * 64 + nt * 16 + l15) * 32 + quad * 8;
            const bf16x8 bh = *(const bf16x8*)&Whs[brow];
            const bf16x8 bl = *(const bf16x8*)&Wls[brow];
#pragma unroll
            for (int mt = 0; mt < 4; ++mt) {
                acc[mt][nt] = MFMA16(ah[mt], bh, acc[mt][nt]);
                acc[mt][nt] = MFMA16(al[mt], bh, acc[mt][nt]);
                acc[mt][nt] = MFMA16(ah[mt], bl, acc[mt][nt]);
            }
        }
    }

    const int hh = ((blockIdx.y & 7) << 1) + wn;     // head index
    if (which < 2) {
        short* Hd = (which == 0) ? Qh : Kh;
        short* Ld = (which == 0) ? Ql : Kl;
        const float qscale = (which == 0) ? 0.125f : 1.0f;
#pragma unroll
        for (int mt = 0; mt < 4; ++mt)
#pragma unroll
            for (int p = 0; p < 2; ++p) {
                const int d1 = p * 16 + l15, d2 = d1 + 32;
                const int col1 = n0 + wn * 64 + d1;
                const float b1 = bias[col1], b2 = bias[col1 + 32];
#pragma unroll
                for (int r = 0; r < 4; ++r) {
                    const int m = m0 + wm * 64 + mt * 16 + quad * 4 + r;
                    const int bb = m >> 11, tg = m & (T_SZ - 1);
                    const float c1 = cosb[tg * 64 + d1], s1 = sinb[tg * 64 + d1];
                    const float c2 = cosb[tg * 64 + d2], s2 = sinb[tg * 64 + d2];
                    const float x1 = acc[mt][p][r] + b1;
                    const float x2 = acc[mt][p + 2][r] + b2;
                    const float y1 = (x1 * c1 - x2 * s1) * qscale;
                    const float y2 = (x2 * c2 + x1 * s2) * qscale;
                    const size_t base = (((size_t)(bb * H_SZ + hh)) * T_SZ + tg) * 64;
                    short h_, l_;
                    split1(y1, &h_, &l_); Hd[base + d1] = h_; Ld[base + d1] = l_;
                    split1(y2, &h_, &l_); Hd[base + d2] = h_; Ld[base + d2] = l_;
                }
            }
    } else {
#pragma unroll
        for (int nt = 0; nt < 4; ++nt) {
            const int d = nt * 16 + l15;
            const float bvv = bias[n0 + wn * 64 + d];
#pragma unroll
            for (int mt = 0; mt < 4; ++mt)
#pragma unroll
                for (int r = 0; r < 4; ++r) {
                    const int m = m0 + wm * 64 + mt * 16 + quad * 4 + r;
                    const int bb = m >> 11, tg = m & (T_SZ - 1);
                    Vb[(((size_t)(bb * H_SZ + hh)) * T_SZ + tg) * 64 + d] =
                        f2bf(acc[mt][nt][r] + bvv);
                }
        }
    }
}

// ---------------------------------------------------------------------------
// Output projection GEMM (fp32 A, split-bf16 W), flat [M,1024] store.
// ---------------------------------------------------------------------------
__global__ __launch_bounds__(256)
void gemm_out_kernel(const float* __restrict__ A, const short* __restrict__ Wh,
                     const short* __restrict__ Wl, const float* __restrict__ bias,
                     float* __restrict__ C)
{
    __shared__ __align__(16) short Whs[128 * 32];
    __shared__ __align__(16) short Wls[128 * 32];

    const int m0 = blockIdx.x * 128, n0 = blockIdx.y * 128;
    const int tid = threadIdx.x;
    const int wv = tid >> 6, lane = tid & 63;
    const int wm = wv >> 1, wn = wv & 1;
    const int l15 = lane & 15, quad = lane >> 4;

    f32x4 acc[4][4];
#pragma unroll
    for (int mt = 0; mt < 4; ++mt)
#pragma unroll
        for (int nt = 0; nt < 4; ++nt)
            acc[mt][nt] = (f32x4){0.f, 0.f, 0.f, 0.f};

    const short* whg = Wh + (size_t)(n0 + wv * 32 + (lane >> 2)) * D_SZ + (lane & 3) * 8;
    const short* wlg = Wl + (size_t)(n0 + wv * 32 + (lane >> 2)) * D_SZ + (lane & 3) * 8;
    short* whl0 = &Whs[wv * 1024];
    short* wll0 = &Wls[wv * 1024];

    const float* aB[4];
#pragma unroll
    for (int mt = 0; mt < 4; ++mt)
        aB[mt] = A + (size_t)(m0 + wm * 64 + mt * 16 + l15) * D_SZ + quad * 8;

    for (int k0 = 0; k0 < D_SZ; k0 += 32) {
        float4 af0[4], af1[4];
#pragma unroll
        for (int mt = 0; mt < 4; ++mt) {
            af0[mt] = *(const float4*)(aB[mt] + k0);
            af1[mt] = *(const float4*)(aB[mt] + k0 + 4);
        }
        __syncthreads();
        GLDS16(whg + k0,             whl0);
        GLDS16(whg + 16 * D_SZ + k0, whl0 + 512);
        GLDS16(wlg + k0,             wll0);
        GLDS16(wlg + 16 * D_SZ + k0, wll0 + 512);

        bf16x8 ah[4], al[4];
#pragma unroll
        for (int mt = 0; mt < 4; ++mt)
            split8(af0[mt], af1[mt], &ah[mt], &al[mt]);

        __syncthreads();

#pragma unroll
        for (int nt = 0; nt < 4; ++nt) {
            const int brow = (wn * 64 + nt * 16 + l15) * 32 + quad * 8;
            const bf16x8 bh = *(const bf16x8*)&Whs[brow];
            const bf16x8 bl = *(const bf16x8*)&Wls[brow];
#pragma unroll
            for (int mt = 0; mt < 4; ++mt) {
                acc[mt][nt] = MFMA16(ah[mt], bh, acc[mt][nt]);
                acc[mt][nt] = MFMA16(al[mt], bh, acc[mt][nt]);
                acc[mt][nt] = MFMA16(ah[mt], bl, acc[mt][nt]);
            }
        }
    }

#pragma unroll
    for (int nt = 0; nt < 4; ++nt) {
        const int col = n0 + wn * 64 + nt * 16 + l15;
        const float bvv = bias[col];
#pragma unroll
        for (int mt = 0; mt < 4; ++mt)
#pragma unroll
            for (int r = 0; r < 4; ++r) {
                const int m = m0 + wm * 64 + mt * 16 + quad * 4 + r;
                C[(size_t)m * D_SZ + col] = acc[mt][nt][r] + bvv;
            }
    }
}

// ---------------------------------------------------------------------------
// MFMA flash attention, conversion-free inner loop.
// Inputs pre-split bf16: Qh/Ql (pre-scaled 1/8), Kh/Kl, Vb  [b,h][t][64].
// Mask consulted only when the per-tile flag is set.
// ---------------------------------------------------------------------------
__global__ __launch_bounds__(256)
void attn_mfma_kernel(const short* __restrict__ Qhg, const short* __restrict__ Qlg,
                      const short* __restrict__ Khg, const short* __restrict__ Klg,
                      const short* __restrict__ Vg,
                      const unsigned char* __restrict__ mask,
                      const int* __restrict__ flags,
                      float* __restrict__ ob)
{
    __shared__ __align__(16) short Khs[64 * 72];
    __shared__ __align__(16) short Kls[64 * 72];
    __shared__ __align__(16) short Vt[64 * 72];       // [d][t]
    __shared__ __align__(16) short Ps[4 * 16 * 72];   // per-wave P tiles

    const int bh = blockIdx.y;
    const int b = bh >> 4, h = bh & 15;
    const int q0 = blockIdx.x * 64;
    const int tid = threadIdx.x;
    const int wv = tid >> 6, lane = tid & 63;
    const int l15 = lane & 15, quad = lane >> 4;

    // Q fragments: direct bf16 loads (A-layout: m=l15, k=quad*8+j)
    const short* qhp = Qhg + ((size_t)bh * T_SZ + q0 + wv * 16 + l15) * 64 + quad * 8;
    const short* qlp = Qlg + ((size_t)bh * T_SZ + q0 + wv * 16 + l15) * 64 + quad * 8;
    bf16x8 qh[2], ql[2];
#pragma unroll
    for (int s = 0; s < 2; ++s) {
        qh[s] = *(const bf16x8*)(qhp + 32 * s);
        ql[s] = *(const bf16x8*)(qlp + 32 * s);
    }

    f32x4 accO[4];
#pragma unroll
    for (int nt = 0; nt < 4; ++nt) accO[nt] = (f32x4){0.f, 0.f, 0.f, 0.f};
    float m_i[4], l_i[4];
#pragma unroll
    for (int r = 0; r < 4; ++r) { m_i[r] = -1e30f; l_i[r] = 0.f; }

    const short* khb = Khg + (size_t)bh * T_SZ * 64;
    const short* klb = Klg + (size_t)bh * T_SZ * 64;
    const short* vb  = Vg  + (size_t)bh * T_SZ * 64;
    const unsigned char* mbase = mask + ((size_t)b * T_SZ + q0) * T_SZ;
    const int* frow = flags + ((size_t)b * 32 + blockIdx.x) * 32;

    // V transpose staging assignment: 4x4 block per thread
    const int vt0 = (tid >> 4) * 4, vd0 = (tid & 15) * 4;
    short* pw = &Ps[wv * 16 * 72];

    for (int kti = 0; kti < 32; ++kti) {
        const int kt = kti * 64;
        __syncthreads();
        // ---- K stage: bf16 copy, 4x (16B load + ds_write_b128)
#pragma unroll
        for (int jj = 0; jj < 4; ++jj) {
            const short* g = (jj < 2) ? khb : klb;
            short* lds = (jj < 2) ? Khs : Kls;
            const int cc = tid + 256 * (jj & 1);
            const int row = cc >> 3, off = (cc & 7) * 8;
            *(bf16x8*)(lds + row * 72 + off) =
                *(const bf16x8*)(g + (size_t)(kt + row) * 64 + off);
        }
        // ---- V stage: register 4x4 transpose -> Vt[d][t]
        {
            uint2 rv[4];
#pragma unroll
            for (int i = 0; i < 4; ++i)
                rv[i] = *(const uint2*)(vb + (size_t)(kt + vt0 + i) * 64 + vd0);
#pragma unroll
            for (int c = 0; c < 4; ++c) {
                const int k = c >> 1;
                const unsigned sel = (c & 1) ? 0x07060302u : 0x05040100u;
                const unsigned lo0 = k ? rv[0].y : rv[0].x;
                const unsigned lo1 = k ? rv[1].y : rv[1].x;
                const unsigned lo2 = k ? rv[2].y : rv[2].x;
                const unsigned lo3 = k ? rv[3].y : rv[3].x;
                uint2 o;
                o.x = __builtin_amdgcn_perm(lo1, lo0, sel);  // (t0.c, t1.c)
                o.y = __builtin_amdgcn_perm(lo3, lo2, sel);  // (t2.c, t3.c)
                *(uint2*)&Vt[(vd0 + c) * 72 + vt0] = o;
            }
        }
        __syncthreads();

        // ---- S = Q K^T (split bf16, 3 products; scale pre-folded into Q)
        f32x4 accS[4];
#pragma unroll
        for (int nt = 0; nt < 4; ++nt) {
            f32x4 acc = (f32x4){0.f, 0.f, 0.f, 0.f};
#pragma unroll
            for (int s = 0; s < 2; ++s) {
                const bf16x8 kh = *(const bf16x8*)&Khs[(nt * 16 + l15) * 72 + 32 * s + quad * 8];
                const bf16x8 kl = *(const bf16x8*)&Kls[(nt * 16 + l15) * 72 + 32 * s + quad * 8];
                acc = MFMA16(qh[s], kh, acc);
                acc = MFMA16(ql[s], kh, acc);
                acc = MFMA16(qh[s], kl, acc);
            }
            accS[nt] = acc;
        }

        float sv[4][4];   // [nt][r]
        if (frow[kti]) {  // rare masked path
#pragma unroll
            for (int nt = 0; nt < 4; ++nt)
#pragma unroll
                for (int r = 0; r < 4; ++r) {
                    const unsigned char mb =
                        mbase[(size_t)(wv * 16 + quad * 4 + r) * T_SZ + kt + nt * 16 + l15];
                    sv[nt][r] = mb ? -1e30f : accS[nt][r];
                }
        } else {
#pragma unroll
            for (int nt = 0; nt < 4; ++nt)
#pragma unroll
                for (int r = 0; r < 4; ++r)
                    sv[nt][r] = accS[nt][r];
        }

        // ---- online softmax; only the row-max is cross-lane per tile
        float rmax[4];
#pragma unroll
        for (int r = 0; r < 4; ++r)
            rmax[r] = fmaxf(fmaxf(sv[0][r], sv[1][r]), fmaxf(sv[2][r], sv[3][r]));
#pragma unroll
        for (int off = 1; off < 16; off <<= 1)
#pragma unroll
            for (int r = 0; r < 4; ++r)
                rmax[r] = fmaxf(rmax[r], __shfl_xor(rmax[r], off, 64));

        float alpha[4];
#pragma unroll
        for (int r = 0; r < 4; ++r) {
            const float mnew = fmaxf(m_i[r], rmax[r]);
            alpha[r] = __expf(m_i[r] - mnew);
            m_i[r] = mnew;
        }
        float lsum[4] = {0.f, 0.f, 0.f, 0.f};
#pragma unroll
        for (int nt = 0; nt < 4; ++nt)
#pragma unroll
            for (int r = 0; r < 4; ++r) {
                const float p = __expf(sv[nt][r] - m_i[r]);
                sv[nt][r] = p;
                lsum[r] += p;
            }
#pragma unroll
        for (int r = 0; r < 4; ++r)
            l_i[r] = l_i[r] * alpha[r] + lsum[r];   // lane-partial; reduced at end

        // ---- P -> bf16 (round-half-up) -> per-wave LDS tile
#pragma unroll
        for (int nt = 0; nt < 4; ++nt)
#pragma unroll
            for (int r = 0; r < 4; ++r) {
                fui u; u.f = sv[nt][r];
                pw[(quad * 4 + r) * 72 + nt * 16 + l15] = (short)((u.u + 0x8000u) >> 16);
            }

        // ---- O = O*alpha + P @ V
#pragma unroll
        for (int nt = 0; nt < 4; ++nt)
#pragma unroll
            for (int r = 0; r < 4; ++r)
                accO[nt][r] *= alpha[r];

        bf16x8 pa[2];
#pragma unroll
        for (int s = 0; s < 2; ++s)
            pa[s] = *(const bf16x8*)&pw[l15 * 72 + 32 * s + quad * 8];
#pragma unroll
        for (int nt = 0; nt < 4; ++nt)
#pragma unroll
            for (int s = 0; s < 2; ++s) {
                const bf16x8 vf = *(const bf16x8*)&Vt[(nt * 16 + l15) * 72 + 32 * s + quad * 8];
                accO[nt] = MFMA16(pa[s], vf, accO[nt]);
            }
    }

    // final cross-lane reduction of l partials (m_i already lane-uniform)
#pragma unroll
    for (int off = 1; off < 16; off <<= 1)
#pragma unroll
        for (int r = 0; r < 4; ++r)
            l_i[r] += __shfl_xor(l_i[r], off, 64);

#pragma unroll
    for (int r = 0; r < 4; ++r) {
        const float inv = 1.f / l_i[r];
        const int t = q0 + wv * 16 + quad * 4 + r;
        float* orow = ob + ((size_t)(b * T_SZ + t)) * D_SZ + h * DK_SZ;
#pragma unroll
        for (int nt = 0; nt < 4; ++nt)
            orow[nt * 16 + l15] = accO[nt][r] * inv;
    }
}

// ---------------------------------------------------------------------------
extern "C" void kernel_launch(void* const* d_in, const int* in_sizes, int n_in,
                              void* d_out, int out_size, void* d_ws, size_t ws_size,
                              hipStream_t stream)
{
    const float* query = (const float*)d_in[0];
    const float* key   = (const float*)d_in[1];
    const float* value = (const float*)d_in[2];
    const float* cosb  = (const float*)d_in[3];
    const float* sinb  = (const float*)d_in[4];
    const unsigned char* mask = (const unsigned char*)d_in[5];
    const float* Wq = (const float*)d_in[6];
    const float* bq = (const float*)d_in[7];
    const float* Wk = (const float*)d_in[8];
    const float* bk = (const float*)d_in[9];
    const float* Wv = (const float*)d_in[10];
    const float* bv = (const float*)d_in[11];
    const float* Wo = (const float*)d_in[12];
    const float* bo = (const float*)d_in[13];
    float* out = (float*)d_out;

    // workspace layout (bytes): 5x bf16 bufs (80MB) | abuf fp32 (32MB) |
    // 8x weight splits (16MB) | flags (16KB)  -> ~128MB total
    short* sp = (short*)d_ws;
    const size_t eb = (size_t)B_SZ * H_SZ * T_SZ * DK_SZ;   // 8388608 elems
    short* Qh = sp;          short* Ql = sp + eb;
    short* Kh = sp + 2 * eb; short* Kl = sp + 3 * eb;
    short* Vb = sp + 4 * eb;
    float* abuf = (float*)(sp + 5 * eb);
    short* wsp = (short*)(abuf + eb);
    const size_t wlen = (size_t)D_SZ * D_SZ;
    short* wqh = wsp;            short* wql = wsp + wlen;
    short* wkh = wsp + 2 * wlen; short* wkl = wsp + 3 * wlen;
    short* wvh = wsp + 4 * wlen; short* wvl = wsp + 5 * wlen;
    short* woh = wsp + 6 * wlen; short* wol = wsp + 7 * wlen;
    int* flags = (int*)(wsp + 8 * wlen);

    const int wsBlocks = (int)(wlen / 4 / 256);
    wsplit_kernel<<<wsBlocks, 256, 0, stream>>>(Wq, wqh, wql);
    wsplit_kernel<<<wsBlocks, 256, 0, stream>>>(Wk, wkh, wkl);
    wsplit_kernel<<<wsBlocks, 256, 0, stream>>>(Wv, wvh, wvl);
    wsplit_kernel<<<wsBlocks, 256, 0, stream>>>(Wo, woh, wol);

    mask_flags_kernel<<<1024, 256, 0, stream>>>(mask, flags);

    qkv_mfma_kernel<<<dim3(M_SZ / 128, 24), 256, 0, stream>>>(
        query, key, value, wqh, wql, wkh, wkl, wvh, wvl,
        bq, bk, bv, cosb, sinb, Qh, Ql, Kh, Kl, Vb);

    attn_mfma_kernel<<<dim3(T_SZ / 64, B_SZ * H_SZ), 256, 0, stream>>>(
        Qh, Ql, Kh, Kl, Vb, mask, flags, abuf);

    gemm_out_kernel<<<dim3(M_SZ / 128, D_SZ / 128), 256, 0, stream>>>(
        abuf, woh, wol, bo, out);
}